// Round 4
// baseline (535.645 us; speedup 1.0000x reference)
//
#include <hip/hip_runtime.h>

// Problem constants (from reference setup_inputs) — all tensors fp32
// (confirmed R3: WRITE_SIZE == out_size*4B, fp32 path passed absmax 7.8e-3).
#define B_ 4
#define C_ 256
#define H_ 200
#define W_ 272
#define HW_ (H_ * W_)        // 54400
#define OH 7
#define OW 7
#define NROI 1024
// SPATIAL_SCALE = 0.25, SAMPLE_NUM = 2

// ---------------- Kernel 1: NCHW -> NHWC transpose ----------------
// in[b][c][hw] -> out[b][hw][c]; classic 32x32 LDS tile per (b, c-tile, hw-tile).
__global__ __launch_bounds__(256) void nchw_to_nhwc(
    const float* __restrict__ in, float* __restrict__ out) {
  __shared__ float tile[32][33];
  int hw0 = blockIdx.x * 32;     // 54400/32 = 1700 tiles
  int c0  = blockIdx.y * 32;     // 256/32 = 8 tiles
  int b   = blockIdx.z;          // 4
  int t = threadIdx.x;

  int lhw = t & 31, lc = t >> 5;         // read: 8 c-rows x 32 hw per iter
#pragma unroll
  for (int i = 0; i < 4; ++i) {
    int c = c0 + lc + i * 8;
    tile[lc + i * 8][lhw] = in[((size_t)b * C_ + c) * HW_ + hw0 + lhw];
  }
  __syncthreads();
  int wc = t & 31, whw = t >> 5;         // write: 8 hw-rows x 32 c per iter
#pragma unroll
  for (int i = 0; i < 4; ++i) {
    int hw = hw0 + whw + i * 8;
    out[((size_t)b * HW_ + hw) * C_ + c0 + wc] = tile[wc][whw + i * 8];
  }
}

// ---------------- Kernel 2: per-ROI gather from NHWC ----------------
// One block per ROI; lane = channel. Every bilinear corner load is a fully
// coalesced 1 KB read (256 contiguous channels of one pixel). Results staged
// in LDS [c][s] (stride 51 => conflict-free) then flushed as one contiguous
// 50 KB coalesced store.
__global__ __launch_bounds__(256) void roi_gather_nhwc(
    const float* __restrict__ nhwc, const float* __restrict__ rois,
    float* __restrict__ out) {
  __shared__ float acc[C_ * 51];  // 52224 B -> 3 blocks/CU
  int n = blockIdx.x;
  int c = threadIdx.x;

  const float* r = rois + (size_t)n * 5;
  int   b  = (int)r[0];
  float x1 = r[1] * 0.25f;
  float y1 = r[2] * 0.25f;
  float x2 = r[3] * 0.25f;
  float y2 = r[4] * 0.25f;
  float bin_w = fmaxf(x2 - x1, 1.0f) * (1.0f / 7.0f);
  float bin_h = fmaxf(y2 - y1, 1.0f) * (1.0f / 7.0f);

  const float* fb = nhwc + (size_t)b * HW_ * C_ + c;

  for (int s = 0; s < 49; ++s) {
    int ph = s / 7, pw = s % 7;
    float sum = 0.0f;
#pragma unroll
    for (int iy = 0; iy < 2; ++iy) {
      float ys = y1 + ((float)(ph * 2 + iy) + 0.5f) * 0.5f * bin_h;
      bool vy = (ys > -1.0f) && (ys < (float)H_);
      float y  = fminf(fmaxf(ys, 0.0f), (float)(H_ - 1));
      float y0f = fminf(floorf(y), (float)(H_ - 2));
      float ly = y - y0f;
      float hy = 1.0f - ly;
      int y0 = (int)y0f;
#pragma unroll
      for (int ix = 0; ix < 2; ++ix) {
        float xs = x1 + ((float)(pw * 2 + ix) + 0.5f) * 0.5f * bin_w;
        bool vx = (xs > -1.0f) && (xs < (float)W_);
        float x  = fminf(fmaxf(xs, 0.0f), (float)(W_ - 1));
        float x0f = fminf(floorf(x), (float)(W_ - 2));
        float lx = x - x0f;
        float hx = 1.0f - lx;
        int x0 = (int)x0f;

        const float* p = fb + (size_t)(y0 * W_ + x0) * C_;
        float v00 = p[0];
        float v01 = p[C_];
        float v10 = p[W_ * C_];
        float v11 = p[W_ * C_ + C_];
        float v = hy * (hx * v00 + lx * v01) + ly * (hx * v10 + lx * v11);
        if (vy && vx) sum += v;
      }
    }
    acc[c * 51 + s] = sum * 0.25f;
  }
  __syncthreads();

  // flush: out[n*12544 + j], j = c*49 + s  (contiguous, coalesced)
  float* o = out + (size_t)n * (C_ * 49);
  for (int j = c; j < C_ * 49; j += 256) {
    int cc = j / 49;
    int ss = j - cc * 49;
    o[j] = acc[cc * 51 + ss];
  }
}

// ---------------- Fallback: direct NCHW kernel (R3-proven) ----------------
__global__ __launch_bounds__(256) void roi_align_direct(
    const float* __restrict__ feats, const float* __restrict__ rois,
    float* __restrict__ out, int total) {
  int idx = blockIdx.x * blockDim.x + threadIdx.x;
  if (idx >= total) return;
  int pw = idx % OW;
  int ph = (idx / OW) % OH;
  int c  = (idx / (OW * OH)) % C_;
  int n  = idx / (OW * OH * C_);

  const float* r = rois + (size_t)n * 5;
  int   b  = (int)r[0];
  float x1 = r[1] * 0.25f;
  float y1 = r[2] * 0.25f;
  float x2 = r[3] * 0.25f;
  float y2 = r[4] * 0.25f;
  float bin_w = fmaxf(x2 - x1, 1.0f) * (1.0f / 7.0f);
  float bin_h = fmaxf(y2 - y1, 1.0f) * (1.0f / 7.0f);

  const float* fp = feats + ((size_t)b * C_ + c) * (size_t)HW_;
  float sum = 0.0f;
#pragma unroll
  for (int iy = 0; iy < 2; ++iy) {
    float ys = y1 + ((float)(ph * 2 + iy) + 0.5f) * 0.5f * bin_h;
    bool vy = (ys > -1.0f) && (ys < (float)H_);
    float y  = fminf(fmaxf(ys, 0.0f), (float)(H_ - 1));
    float y0f = fminf(floorf(y), (float)(H_ - 2));
    float ly = y - y0f, hy = 1.0f - ly;
    int y0 = (int)y0f;
#pragma unroll
    for (int ix = 0; ix < 2; ++ix) {
      float xs = x1 + ((float)(pw * 2 + ix) + 0.5f) * 0.5f * bin_w;
      bool vx = (xs > -1.0f) && (xs < (float)W_);
      float x  = fminf(fmaxf(xs, 0.0f), (float)(W_ - 1));
      float x0f = fminf(floorf(x), (float)(W_ - 2));
      float lx = x - x0f, hx = 1.0f - lx;
      int x0 = (int)x0f;
      const float* p = fp + y0 * W_ + x0;
      float v = hy * (hx * p[0] + lx * p[1]) + ly * (hx * p[W_] + lx * p[W_ + 1]);
      if (vy && vx) sum += v;
    }
  }
  out[idx] = sum * 0.25f;
}

extern "C" void kernel_launch(void* const* d_in, const int* in_sizes, int n_in,
                              void* d_out, int out_size, void* d_ws, size_t ws_size,
                              hipStream_t stream) {
  const float* feats = (const float*)d_in[0];
  const float* rois  = (const float*)d_in[1];
  float* out = (float*)d_out;

  const size_t nhwc_bytes = (size_t)B_ * HW_ * C_ * sizeof(float);  // 55,705,600

  if (ws_size >= nhwc_bytes) {
    float* nhwc = (float*)d_ws;
    dim3 tgrid(HW_ / 32, C_ / 32, B_);
    nchw_to_nhwc<<<tgrid, 256, 0, stream>>>(feats, nhwc);
    roi_gather_nhwc<<<NROI, 256, 0, stream>>>(nhwc, rois, out);
  } else {
    int total = out_size;  // N*C*7*7
    roi_align_direct<<<(total + 255) / 256, 256, 0, stream>>>(feats, rois, out, total);
  }
}

// Round 5
// 455.208 us; speedup vs baseline: 1.1767x; 1.1767x over previous
//
#include <hip/hip_runtime.h>

// Problem constants (fp32 confirmed R3). NCHW features (4,256,200,272),
// rois (1024,5), out (1024,256,7,7). SPATIAL_SCALE=0.25, SAMPLE_NUM=2.
#define B_ 4
#define C_ 256
#define H_ 200
#define W_ 272
#define HW_ (H_ * W_)        // 54400
#define OH 7
#define OW 7
#define NROI 1024

// ---------------- Kernel 1: NCHW -> NHWC transpose, float4 both sides ------
// Block: 32 c x 128 hw (four 32x32 LDS sub-transposes). Grid (425, 8, 4).
__global__ __launch_bounds__(256) void nchw_to_nhwc(
    const float* __restrict__ in, float* __restrict__ out) {
  __shared__ float tile[32][33];  // [hw_local][c_local], stride 33: <=2-way alias (free)
  int c0 = blockIdx.y * 32;
  int b  = blockIdx.z;
  int t  = threadIdx.x;
#pragma unroll
  for (int sub = 0; sub < 4; ++sub) {
    int hw0 = blockIdx.x * 128 + sub * 32;
    {
      int cl = t >> 3;           // 0..31
      int h8 = (t & 7) * 4;      // 0,4,..,28
      const float4 v =
          *(const float4*)(in + ((size_t)b * C_ + c0 + cl) * HW_ + hw0 + h8);
      tile[h8 + 0][cl] = v.x;
      tile[h8 + 1][cl] = v.y;
      tile[h8 + 2][cl] = v.z;
      tile[h8 + 3][cl] = v.w;
    }
    __syncthreads();
    {
      int hl = t >> 3;
      int c8 = (t & 7) * 4;
      float4 v;
      v.x = tile[hl][c8 + 0];
      v.y = tile[hl][c8 + 1];
      v.z = tile[hl][c8 + 2];
      v.w = tile[hl][c8 + 3];
      *(float4*)(out + ((size_t)b * HW_ + hw0 + hl) * C_ + c0 + c8) = v;
    }
    __syncthreads();
  }
}

// ---------------- Kernel 2: per-(ROI, ph-row) gather from NHWC --------------
// Grid (1024, 7). Lane = channel. Per bin: 16 independent coalesced 1KB loads
// issued together (MLP), then weighted combine. LDS 7KB -> occupancy not
// LDS-capped. Flush coalesced-ish (28B runs) to out[n][c][ph*7+pw].
__global__ __launch_bounds__(256) void roi_gather_nhwc(
    const float* __restrict__ nhwc, const float* __restrict__ rois,
    float* __restrict__ out) {
  __shared__ float acc[C_ * OW];  // 7168 B
  int n  = blockIdx.x;
  int ph = blockIdx.y;
  int c  = threadIdx.x;

  const float* r = rois + (size_t)n * 5;
  int   b  = (int)r[0];
  float x1 = r[1] * 0.25f;
  float y1 = r[2] * 0.25f;
  float x2 = r[3] * 0.25f;
  float y2 = r[4] * 0.25f;
  float bin_w = fmaxf(x2 - x1, 1.0f) * (1.0f / 7.0f);
  float bin_h = fmaxf(y2 - y1, 1.0f) * (1.0f / 7.0f);

  // y samples for this ph (hoisted: shared by all 7 bins of the row)
  float ys0 = y1 + ((float)(ph * 2 + 0) + 0.5f) * 0.5f * bin_h;
  float ys1 = y1 + ((float)(ph * 2 + 1) + 0.5f) * 0.5f * bin_h;
  float my0 = ((ys0 > -1.0f) && (ys0 < (float)H_)) ? 1.0f : 0.0f;
  float my1 = ((ys1 > -1.0f) && (ys1 < (float)H_)) ? 1.0f : 0.0f;
  float ya  = fminf(fmaxf(ys0, 0.0f), (float)(H_ - 1));
  float yb  = fminf(fmaxf(ys1, 0.0f), (float)(H_ - 1));
  float y0fa = fminf(floorf(ya), (float)(H_ - 2));
  float y0fb = fminf(floorf(yb), (float)(H_ - 2));
  float lya = ya - y0fa, hya = 1.0f - lya;
  float lyb = yb - y0fb, hyb = 1.0f - lyb;
  int ra = (int)y0fa, rb = (int)y0fb;

  const float* fb0 = nhwc + (size_t)b * HW_ * C_ + c;
  const float* row0 = fb0 + (size_t)(ra * W_) * C_;        // iy=0, y0
  const float* row1 = fb0 + (size_t)((ra + 1) * W_) * C_;  // iy=0, y0+1
  const float* row2 = fb0 + (size_t)(rb * W_) * C_;        // iy=1, y0
  const float* row3 = fb0 + (size_t)((rb + 1) * W_) * C_;  // iy=1, y0+1

  for (int pw = 0; pw < OW; ++pw) {
    float xs0 = x1 + ((float)(pw * 2 + 0) + 0.5f) * 0.5f * bin_w;
    float xs1 = x1 + ((float)(pw * 2 + 1) + 0.5f) * 0.5f * bin_w;
    float mx0 = ((xs0 > -1.0f) && (xs0 < (float)W_)) ? 1.0f : 0.0f;
    float mx1 = ((xs1 > -1.0f) && (xs1 < (float)W_)) ? 1.0f : 0.0f;
    float xa  = fminf(fmaxf(xs0, 0.0f), (float)(W_ - 1));
    float xb  = fminf(fmaxf(xs1, 0.0f), (float)(W_ - 1));
    float x0fa = fminf(floorf(xa), (float)(W_ - 2));
    float x0fb = fminf(floorf(xb), (float)(W_ - 2));
    float lxa = xa - x0fa, hxa = 1.0f - lxa;
    float lxb = xb - x0fb, hxb = 1.0f - lxb;
    int ca = (int)x0fa * C_;
    int cb = (int)x0fb * C_;

    // 16 independent coalesced loads (4 y-rows x 4 x-cols)
    float v0a = row0[ca], v0a1 = row0[ca + C_], v0b = row0[cb], v0b1 = row0[cb + C_];
    float v1a = row1[ca], v1a1 = row1[ca + C_], v1b = row1[cb], v1b1 = row1[cb + C_];
    float v2a = row2[ca], v2a1 = row2[ca + C_], v2b = row2[cb], v2b1 = row2[cb + C_];
    float v3a = row3[ca], v3a1 = row3[ca + C_], v3b = row3[cb], v3b1 = row3[cb + C_];

    float s00 = hya * (hxa * v0a + lxa * v0a1) + lya * (hxa * v1a + lxa * v1a1);
    float s01 = hya * (hxb * v0b + lxb * v0b1) + lya * (hxb * v1b + lxb * v1b1);
    float s10 = hyb * (hxa * v2a + lxa * v2a1) + lyb * (hxa * v3a + lxa * v3a1);
    float s11 = hyb * (hxb * v2b + lxb * v2b1) + lyb * (hxb * v3b + lxb * v3b1);

    float sum = my0 * (mx0 * s00 + mx1 * s01) + my1 * (mx0 * s10 + mx1 * s11);
    acc[c * OW + pw] = sum * 0.25f;
  }
  __syncthreads();

  float* o = out + (size_t)n * (C_ * OH * OW) + ph * OW;
  for (int j = c; j < C_ * OW; j += 256) {
    int cc = j / OW;
    int pwj = j - cc * OW;
    o[cc * (OH * OW) + pwj] = acc[j];
  }
}

// ---------------- Fallback: direct NCHW kernel (R3-proven) ----------------
__global__ __launch_bounds__(256) void roi_align_direct(
    const float* __restrict__ feats, const float* __restrict__ rois,
    float* __restrict__ out, int total) {
  int idx = blockIdx.x * blockDim.x + threadIdx.x;
  if (idx >= total) return;
  int pw = idx % OW;
  int ph = (idx / OW) % OH;
  int c  = (idx / (OW * OH)) % C_;
  int n  = idx / (OW * OH * C_);

  const float* r = rois + (size_t)n * 5;
  int   b  = (int)r[0];
  float x1 = r[1] * 0.25f;
  float y1 = r[2] * 0.25f;
  float x2 = r[3] * 0.25f;
  float y2 = r[4] * 0.25f;
  float bin_w = fmaxf(x2 - x1, 1.0f) * (1.0f / 7.0f);
  float bin_h = fmaxf(y2 - y1, 1.0f) * (1.0f / 7.0f);

  const float* fp = feats + ((size_t)b * C_ + c) * (size_t)HW_;
  float sum = 0.0f;
#pragma unroll
  for (int iy = 0; iy < 2; ++iy) {
    float ys = y1 + ((float)(ph * 2 + iy) + 0.5f) * 0.5f * bin_h;
    bool vy = (ys > -1.0f) && (ys < (float)H_);
    float y  = fminf(fmaxf(ys, 0.0f), (float)(H_ - 1));
    float y0f = fminf(floorf(y), (float)(H_ - 2));
    float ly = y - y0f, hy = 1.0f - ly;
    int y0 = (int)y0f;
#pragma unroll
    for (int ix = 0; ix < 2; ++ix) {
      float xs = x1 + ((float)(pw * 2 + ix) + 0.5f) * 0.5f * bin_w;
      bool vx = (xs > -1.0f) && (xs < (float)W_);
      float x  = fminf(fmaxf(xs, 0.0f), (float)(W_ - 1));
      float x0f = fminf(floorf(x), (float)(W_ - 2));
      float lx = x - x0f, hx = 1.0f - lx;
      int x0 = (int)x0f;
      const float* p = fp + y0 * W_ + x0;
      float v = hy * (hx * p[0] + lx * p[1]) + ly * (hx * p[W_] + lx * p[W_ + 1]);
      if (vy && vx) sum += v;
    }
  }
  out[idx] = sum * 0.25f;
}

extern "C" void kernel_launch(void* const* d_in, const int* in_sizes, int n_in,
                              void* d_out, int out_size, void* d_ws, size_t ws_size,
                              hipStream_t stream) {
  const float* feats = (const float*)d_in[0];
  const float* rois  = (const float*)d_in[1];
  float* out = (float*)d_out;

  const size_t nhwc_bytes = (size_t)B_ * HW_ * C_ * sizeof(float);  // 55,705,600

  if (ws_size >= nhwc_bytes) {
    float* nhwc = (float*)d_ws;
    dim3 tgrid(HW_ / 128, C_ / 32, B_);  // (425, 8, 4)
    nchw_to_nhwc<<<tgrid, 256, 0, stream>>>(feats, nhwc);
    dim3 ggrid(NROI, OH);  // (1024, 7)
    roi_gather_nhwc<<<ggrid, 256, 0, stream>>>(nhwc, rois, out);
  } else {
    int total = out_size;
    roi_align_direct<<<(total + 255) / 256, 256, 0, stream>>>(feats, rois, out, total);
  }
}